// Round 11
// baseline (1786.083 us; speedup 1.0000x reference)
//
#include <hip/hip_runtime.h>
#include <stdint.h>

typedef unsigned long long ull;

// VQ-VAE vector quantizer — fp32 in / fp32 out, np-bitwise-exact (absmax 0).
//   A: numpy scalar pairwise (8 stride-8 accs per 128-block), squares rounded, no FMA.
//   C: np.einsum SSE path: 4 lane-partials (d mod 4), unfused mul+add, hadd tree
//      ((l0+l1)+(l2+l3)). dist = fmaf(-2,C,A) = fl(A-2C); fl(A+B)==A (B < half-ulp).
//   Argmin first-index ties via u64 (dist_bits<<32 | idx) min.
// Round-19: r18's lgkm-only barrier WON (+71us, keep). Remaining stall: waves idle
// ~74% of SIMD time at 12 waves/CU — latency-bound, all in-block levers exhausted.
// Fix: 512-thread blocks (8 waves, py 0..15) -> BM=64 via MORE WAVES at the SAME
// per-thread tile (acc 4x16 = proven 84-95 VGPR budget; r17's 196-VGPR cliff
// avoided). Waves/CU 12 -> up to 24 (LDS 25.6KB x3 = 76.8KB fits; VGPR 84 -> 6/SIMD).
// E staging per MAC halves (8KB chunk feeds 64 rows; 1 float4 + 4 writes/thread).
// launch_bounds(512,2): cap 256, no spill possible. Bank patterns verified 2-way.
// Exactness: pure block-shape remap; per-thread tile, addend order, butterfly,
// fl(A-2C), u64 first-index ties all byte-identical.

constexpr int ZP = 68, EP = 132;   // LDS pitches (floats): Z 64 rows + pad, E as r10
constexpr int BM = 64, BN = 128;

__device__ __forceinline__ float2 pk_mul_lo(float2 a, float2 b) {   // (a.x*b.x, a.x*b.y)
    float2 d;
    asm("v_pk_mul_f32 %0, %1, %2 op_sel:[0,0] op_sel_hi:[0,1]" : "=v"(d) : "v"(a), "v"(b));
    return d;
}
__device__ __forceinline__ float2 pk_mul_hi(float2 a, float2 b) {   // (a.y*b.x, a.y*b.y)
    float2 d;
    asm("v_pk_mul_f32 %0, %1, %2 op_sel:[1,0] op_sel_hi:[1,1]" : "=v"(d) : "v"(a), "v"(b));
    return d;
}
__device__ __forceinline__ void pk_acc(float2& acc, float2 p) {     // acc += p (per-half RTN)
    asm("v_pk_add_f32 %0, %0, %1" : "+v"(acc) : "v"(p));
}
// LDS-only barrier: drain LDS ops (reads+writes), then raw s_barrier.
// Globals (register-destined) stay in flight — no vmcnt(0) drain. [r18 win]
__device__ __forceinline__ void barrier_lds() {
    asm volatile("s_waitcnt lgkmcnt(0)" ::: "memory");
    __builtin_amdgcn_s_barrier();
}

// ---------------- kernel 1: A[n] = sum_d z[n,d]^2, numpy-pairwise ----------------
__global__ void rowsumsq_kernel(const float* __restrict__ z, float* __restrict__ A,
                                int D, int HW) {
    #pragma clang fp contract(off)
    int n = blockIdx.x * 256 + threadIdx.x;
    int b = n / HW, hw = n % HW;
    const float* p = z + (size_t)b * D * HW + hw;
    if (D == 256) {
        float half[2];
        #pragma unroll
        for (int h = 0; h < 2; ++h) {
            float r[8];
            #pragma unroll
            for (int j = 0; j < 8; ++j) {
                float v = p[(size_t)(h * 128 + j) * HW];
                r[j] = v * v;
            }
            for (int t = 8; t < 128; t += 8) {
                #pragma unroll
                for (int j = 0; j < 8; ++j) {
                    float v = p[(size_t)(h * 128 + t + j) * HW];
                    float s = v * v;
                    r[j] = r[j] + s;
                }
            }
            half[h] = ((r[0] + r[1]) + (r[2] + r[3])) + ((r[4] + r[5]) + (r[6] + r[7]));
        }
        A[n] = half[0] + half[1];
    } else {
        float s = 0.f;
        for (int d = 0; d < D; ++d) { float v = p[(size_t)d * HW]; s = s + v * v; }
        A[n] = s;
    }
}

// ---------------- kernel 2: distance GEMM (512 thr, 8 waves, BM=64) + argmin ----------------
__global__ __launch_bounds__(512, 2)
void dist_kernel(const float* __restrict__ z, const float* __restrict__ cb,
                 const float* __restrict__ A, ull* __restrict__ segkeys,
                 int D, int HW, int segLen, int N) {
    #pragma clang fp contract(off)
    __shared__ float Zs[2][16 * ZP];
    __shared__ float Es[2][16 * EP];
    const int t   = threadIdx.x;
    const int seg = blockIdx.x;
    const int n0  = blockIdx.y * BM;       // 64 | HW => tile within one batch image
    const int bb  = n0 / HW, hw0 = n0 % HW;
    const float* zbase = z + (size_t)bb * D * HW + hw0;

    const int sse = t & 3;                 // numpy SSE lane (d mod 4)
    const int px  = (t >> 2) & 7;          // col group: 16 cols at px*16
    const int py  = t >> 5;                // row group: 4 rows at py*4 (0..15)
    const int zd_s = t >> 5, zn2 = (t & 31) << 1;   // Z staging: 16 d x 32 float2-cols
    const int ek = t >> 2, ed4 = (t & 3) << 2;      // E staging: 128 cols x 4 d each

    float Ar[4];
    #pragma unroll
    for (int r = 0; r < 4; ++r) Ar[r] = A[n0 + (py << 2) + r];
    ull bestk[4] = {~0ull, ~0ull, ~0ull, ~0ull};

    const int kTiles = segLen / BN;
    const int nCh = D >> 4;
    for (int kt = 0; kt < kTiles; ++kt) {
        const int k0 = seg * segLen + kt * BN;
        const float* zp = zbase + (size_t)zd_s * HW + zn2;
        const float* ep = cb + (size_t)(k0 + ek) * D + ed4;
        float2 zr = *(const float2*)zp;            // preload chunk 0
        float4 e0 = *(const float4*)ep;

        float2 acc[4][8];                  // [row][col-pair], ONE sse-lane partial each
        #pragma unroll
        for (int r = 0; r < 4; ++r)
            #pragma unroll
            for (int p = 0; p < 8; ++p) acc[r][p] = make_float2(0.f, 0.f);

        // prologue: stage chunk 0 into buf 0, preload chunk 1
        *(float2*)&Zs[0][zd_s * ZP + zn2] = zr;
        Es[0][(ed4 + 0) * EP + ek] = e0.x;
        Es[0][(ed4 + 1) * EP + ek] = e0.y;
        Es[0][(ed4 + 2) * EP + ek] = e0.z;
        Es[0][(ed4 + 3) * EP + ek] = e0.w;
        if (nCh > 1) {
            zp += (size_t)16 * HW; ep += 16;
            zr = *(const float2*)zp;
            e0 = *(const float4*)ep;
        }
        barrier_lds();                     // buf0 visible; preloads stay in flight

        for (int c = 0; c < nCh; ++c) {
            const int cur = c & 1;
            #pragma unroll
            for (int u = 0; u < 4; ++u) {
                const int dl = sse + (u << 2);     // this lane's d, ascending
                const float* zrow = &Zs[cur][dl * ZP + (py << 2)];
                float2 a01 = *(const float2*)(zrow);
                float2 a23 = *(const float2*)(zrow + 2);
                const float* er = &Es[cur][dl * EP + (px << 4)];
                float2 b0 = *(const float2*)(er + 0);
                float2 b1 = *(const float2*)(er + 2);
                float2 b2 = *(const float2*)(er + 4);
                float2 b3 = *(const float2*)(er + 6);
                pk_acc(acc[0][0], pk_mul_lo(a01, b0));
                pk_acc(acc[1][0], pk_mul_hi(a01, b0));
                pk_acc(acc[2][0], pk_mul_lo(a23, b0));
                pk_acc(acc[3][0], pk_mul_hi(a23, b0));
                pk_acc(acc[0][1], pk_mul_lo(a01, b1));
                pk_acc(acc[1][1], pk_mul_hi(a01, b1));
                pk_acc(acc[2][1], pk_mul_lo(a23, b1));
                pk_acc(acc[3][1], pk_mul_hi(a23, b1));
                pk_acc(acc[0][2], pk_mul_lo(a01, b2));
                pk_acc(acc[1][2], pk_mul_hi(a01, b2));
                pk_acc(acc[2][2], pk_mul_lo(a23, b2));
                pk_acc(acc[3][2], pk_mul_hi(a23, b2));
                pk_acc(acc[0][3], pk_mul_lo(a01, b3));
                pk_acc(acc[1][3], pk_mul_hi(a01, b3));
                pk_acc(acc[2][3], pk_mul_lo(a23, b3));
                pk_acc(acc[3][3], pk_mul_hi(a23, b3));
                float2 b4 = *(const float2*)(er + 8);
                float2 b5 = *(const float2*)(er + 10);
                float2 b6 = *(const float2*)(er + 12);
                float2 b7 = *(const float2*)(er + 14);
                pk_acc(acc[0][4], pk_mul_lo(a01, b4));
                pk_acc(acc[1][4], pk_mul_hi(a01, b4));
                pk_acc(acc[2][4], pk_mul_lo(a23, b4));
                pk_acc(acc[3][4], pk_mul_hi(a23, b4));
                pk_acc(acc[0][5], pk_mul_lo(a01, b5));
                pk_acc(acc[1][5], pk_mul_hi(a01, b5));
                pk_acc(acc[2][5], pk_mul_lo(a23, b5));
                pk_acc(acc[3][5], pk_mul_hi(a23, b5));
                pk_acc(acc[0][6], pk_mul_lo(a01, b6));
                pk_acc(acc[1][6], pk_mul_hi(a01, b6));
                pk_acc(acc[2][6], pk_mul_lo(a23, b6));
                pk_acc(acc[3][6], pk_mul_hi(a23, b6));
                pk_acc(acc[0][7], pk_mul_lo(a01, b7));
                pk_acc(acc[1][7], pk_mul_hi(a01, b7));
                pk_acc(acc[2][7], pk_mul_lo(a23, b7));
                pk_acc(acc[3][7], pk_mul_hi(a23, b7));
            }
            if (c + 1 < nCh) {
                const int nxt = cur ^ 1;
                // write chunk c+1 (preloaded regs) while other waves MAC buf[cur]
                *(float2*)&Zs[nxt][zd_s * ZP + zn2] = zr;
                Es[nxt][(ed4 + 0) * EP + ek] = e0.x;
                Es[nxt][(ed4 + 1) * EP + ek] = e0.y;
                Es[nxt][(ed4 + 2) * EP + ek] = e0.z;
                Es[nxt][(ed4 + 3) * EP + ek] = e0.w;
                if (c + 2 < nCh) {        // in-flight across barrier + next MAC block
                    zp += (size_t)16 * HW; ep += 16;
                    zr = *(const float2*)zp;
                    e0 = *(const float4*)ep;
                }
                barrier_lds();            // chunk c+1 visible; globals stay in flight
            }
        }
        if (nCh & 1) __syncthreads();     // parity guard for odd nCh (no-op at D=256)

        // epilogue: quad butterfly = exact hadd tree ((l0+l1)+(l2+l3)), then keys
        #pragma unroll
        for (int r = 0; r < 4; ++r) {
            #pragma unroll
            for (int p = 0; p < 8; ++p) {
                float2 v = acc[r][p];
                v.x = v.x + __shfl_xor(v.x, 1);
                v.y = v.y + __shfl_xor(v.y, 1);
                v.x = v.x + __shfl_xor(v.x, 2);
                v.y = v.y + __shfl_xor(v.y, 2);
                int col = k0 + (px << 4) + (p << 1);
                float dd0 = fmaf(-2.f, v.x, Ar[r]);   // fl(A - 2C), single rounding
                float dd1 = fmaf(-2.f, v.y, Ar[r]);
                ull kA = ((ull)__float_as_uint(dd0) << 32) | (unsigned)col;
                ull kB = ((ull)__float_as_uint(dd1) << 32) | (unsigned)(col + 1);
                if (kA < bestk[r]) bestk[r] = kA;
                if (kB < bestk[r]) bestk[r] = kB;
            }
        }
    }
    // merge across px groups (offsets 4,8,16 stay within the 32-lane py half-wave)
    #pragma unroll
    for (int r = 0; r < 4; ++r) {
        ull bk = bestk[r];
        #pragma unroll
        for (int off = 4; off <= 16; off <<= 1) {
            ull o = __shfl_xor(bk, off);
            if (o < bk) bk = o;
        }
        if ((t & 31) == 0)
            segkeys[(size_t)seg * N + n0 + (py << 2) + r] = bk;
    }
}

// ---------------- kernel 3: segment-min, gather z_q, STE, idx, loss partials ----------------
__global__ void out_kernel(const float* __restrict__ z, const float* __restrict__ cb,
                           const ull* __restrict__ segkeys,
                           float* __restrict__ out, float* __restrict__ parts,
                           int D, int HW, int K, int N, int nSeg) {
    #pragma clang fp contract(off)
    int n = blockIdx.x * 256 + threadIdx.x;
    int b = n / HW, hw = n % HW;
    ull bk = segkeys[n];
    for (int s = 1; s < nSeg; ++s) {
        ull o = segkeys[(size_t)s * N + n];
        if (o < bk) bk = o;
    }
    size_t zqE = (size_t)N * D;
    int raw = (int)(unsigned int)(bk & 0xffffffffULL);
    int idx = (raw >= 0 && raw < K) ? raw : 0;
    out[zqE + 1 + (size_t)n] = (float)idx;
    const float* zp = z + (size_t)b * D * HW + hw;
    const float* cp = cb + (size_t)idx * D;
    float* op = out + (size_t)b * D * HW + hw;
    float sq = 0.f;
    for (int c4 = 0; c4 < D; c4 += 4) {
        float4 q = *(const float4*)(cp + c4);
        float qv[4] = {q.x, q.y, q.z, q.w};
        #pragma unroll
        for (int i = 0; i < 4; ++i) {
            int c = c4 + i;
            float zv = zp[(size_t)c * HW];
            float diff = qv[i] - zv;
            sq = fmaf(diff, diff, sq);
            op[(size_t)c * HW] = zv + diff;
        }
    }
    #pragma unroll
    for (int off = 32; off; off >>= 1) sq += __shfl_down(sq, off, 64);
    __shared__ float red[4];
    int lane = threadIdx.x & 63, wv = threadIdx.x >> 6;
    if (lane == 0) red[wv] = sq;
    __syncthreads();
    if (threadIdx.x == 0) parts[blockIdx.x] = red[0] + red[1] + red[2] + red[3];
}

// ---------------- kernel 4: loss = mean + 0.25*mean ----------------
__global__ void loss_kernel(const float* __restrict__ parts, float* __restrict__ out,
                            int P, float inv_count, size_t zqE) {
    float v = 0.f;
    for (int i = threadIdx.x; i < P; i += 64) v += parts[i];
    #pragma unroll
    for (int off = 32; off; off >>= 1) v += __shfl_down(v, off, 64);
    if (threadIdx.x == 0) {
        float m = v * inv_count;
        out[zqE] = m + 0.25f * m;
    }
}

extern "C" void kernel_launch(void* const* d_in, const int* in_sizes, int n_in,
                              void* d_out, int out_size, void* d_ws, size_t ws_size,
                              hipStream_t stream) {
    long zE = in_sizes[0], cE = in_sizes[1];
    const float* z  = (const float*)d_in[0];
    const float* cb = (const float*)d_in[1];
    long N = (long)out_size - 1 - zE;
    long D = (N > 0 && zE % N == 0) ? zE / N : 0;
    bool okA = (N > 0) && D >= 16 && (D % 16 == 0) && (cE % D == 0) && (cE / D >= 128);
    if (!okA) {
        long tmp = zE; zE = cE; cE = tmp;
        const float* tp = z; z = cb; cb = tp;
        N = (long)out_size - 1 - zE;
        D = (N > 0 && zE % N == 0) ? zE / N : 1;
    }
    long K = cE / D;
    int HW = (N % 1024 == 0) ? 1024 : (N % 256 == 0 ? 256 : 64);
    float* out = (float*)d_out;

    int nSeg = 8;
    while (nSeg > 1 &&
           ((size_t)nSeg * N * 8 + (size_t)N * 4 + (size_t)(N / 256) * 4 > ws_size ||
            K % ((long)nSeg * BN) != 0))
        nSeg >>= 1;
    int segLen = (int)(K / nSeg);
    ull* segkeys = (ull*)d_ws;
    float* A     = (float*)((char*)d_ws + (size_t)nSeg * N * 8);
    float* parts = (float*)((char*)A + (size_t)N * 4);

    rowsumsq_kernel<<<dim3((int)(N / 256)), 256, 0, stream>>>(z, A, (int)D, HW);
    dist_kernel<<<dim3(nSeg, (int)(N / BM)), 512, 0, stream>>>(z, cb, A, segkeys,
                                                               (int)D, HW, segLen, (int)N);
    out_kernel<<<dim3((int)(N / 256)), 256, 0, stream>>>(z, cb, segkeys, out, parts,
                                                         (int)D, HW, (int)K, (int)N, nSeg);
    double cnt = (double)N * (double)D;
    loss_kernel<<<1, 64, 0, stream>>>(parts, out, (int)(N / 256),
                                      (float)(1.0 / cnt), (size_t)N * (size_t)D);
}

// Round 12
// 1567.065 us; speedup vs baseline: 1.1398x; 1.1398x over previous
//
#include <hip/hip_runtime.h>
#include <stdint.h>

typedef unsigned long long ull;

// VQ-VAE vector quantizer — fp32 in / fp32 out, np-bitwise-exact (absmax 0).
//   A: numpy scalar pairwise (8 stride-8 accs per 128-block), squares rounded, no FMA.
//   C: np.einsum SSE path: 4 lane-partials (d mod 4), unfused mul+add, hadd tree
//      ((l0+l1)+(l2+l3)). dist = fmaf(-2,C,A) = fl(A-2C); fl(A+B)==A (B < half-ulp).
//   Argmin first-index ties via u64 (dist_bits<<32 | idx) min.
// Round-20: r19's 512-thr blocks REVERTED (residency law: achieved = theoretical
// minus one block; 8-wave blocks -> 1 resident block, 24% occ, slower. 12 waves/CU
// at 4-wave blocks is the plateau). Back to r18 (1640us best: lgkm-only barrier).
// NEW: BK=32 staging periods — Zs/Es hold 32 d-rows, MAC 8 u-blocks per period ->
// 64 barriers/block (was 128); 2x longer MAC phases fully shadow the in-flight
// global preloads (which r18's barrier keeps airborne). LDS 44KB x3 = 132 <= 160KB;
// VGPR ~110 under the (256,3) cap, no spill. Exactness: acc addend order remains
// strictly ascending d (32c + sse + 4u); staging placement-only; banks re-verified
// 2-way on writes (row offsets 640/1056/2112 = 0 mod 32), reads unchanged.

constexpr int ZP = 40, EP = 132;   // LDS pitches (floats); r8/r10 layout
constexpr int BM = 32, BN = 128;

__device__ __forceinline__ float2 pk_mul_lo(float2 a, float2 b) {   // (a.x*b.x, a.x*b.y)
    float2 d;
    asm("v_pk_mul_f32 %0, %1, %2 op_sel:[0,0] op_sel_hi:[0,1]" : "=v"(d) : "v"(a), "v"(b));
    return d;
}
__device__ __forceinline__ float2 pk_mul_hi(float2 a, float2 b) {   // (a.y*b.x, a.y*b.y)
    float2 d;
    asm("v_pk_mul_f32 %0, %1, %2 op_sel:[1,0] op_sel_hi:[1,1]" : "=v"(d) : "v"(a), "v"(b));
    return d;
}
__device__ __forceinline__ void pk_acc(float2& acc, float2 p) {     // acc += p (per-half RTN)
    asm("v_pk_add_f32 %0, %0, %1" : "+v"(acc) : "v"(p));
}
// LDS-only barrier: drain LDS ops (reads+writes), then raw s_barrier.
// Globals (register-destined) stay in flight — no vmcnt(0) drain. [r18 win]
__device__ __forceinline__ void barrier_lds() {
    asm volatile("s_waitcnt lgkmcnt(0)" ::: "memory");
    __builtin_amdgcn_s_barrier();
}

// ---------------- kernel 1: A[n] = sum_d z[n,d]^2, numpy-pairwise ----------------
__global__ void rowsumsq_kernel(const float* __restrict__ z, float* __restrict__ A,
                                int D, int HW) {
    #pragma clang fp contract(off)
    int n = blockIdx.x * 256 + threadIdx.x;
    int b = n / HW, hw = n % HW;
    const float* p = z + (size_t)b * D * HW + hw;
    if (D == 256) {
        float half[2];
        #pragma unroll
        for (int h = 0; h < 2; ++h) {
            float r[8];
            #pragma unroll
            for (int j = 0; j < 8; ++j) {
                float v = p[(size_t)(h * 128 + j) * HW];
                r[j] = v * v;
            }
            for (int t = 8; t < 128; t += 8) {
                #pragma unroll
                for (int j = 0; j < 8; ++j) {
                    float v = p[(size_t)(h * 128 + t + j) * HW];
                    float s = v * v;
                    r[j] = r[j] + s;
                }
            }
            half[h] = ((r[0] + r[1]) + (r[2] + r[3])) + ((r[4] + r[5]) + (r[6] + r[7]));
        }
        A[n] = half[0] + half[1];
    } else {
        float s = 0.f;
        for (int d = 0; d < D; ++d) { float v = p[(size_t)d * HW]; s = s + v * v; }
        A[n] = s;
    }
}

// ---------------- kernel 2: distance GEMM (BK=32 periods, lgkm barriers) + argmin ----------------
__global__ __launch_bounds__(256, 3)
void dist_kernel(const float* __restrict__ z, const float* __restrict__ cb,
                 const float* __restrict__ A, ull* __restrict__ segkeys,
                 int D, int HW, int segLen, int N) {
    #pragma clang fp contract(off)
    __shared__ float Zs[2][32 * ZP];
    __shared__ float Es[2][32 * EP];
    const int t   = threadIdx.x;
    const int seg = blockIdx.x;
    const int n0  = blockIdx.y * BM;       // 32 | HW => tile within one batch image
    const int bb  = n0 / HW, hw0 = n0 % HW;
    const float* zbase = z + (size_t)bb * D * HW + hw0;

    const int sse = t & 3;                 // numpy SSE lane (d mod 4)
    const int px  = (t >> 2) & 7;          // col group: 16 cols at px*16
    const int py  = t >> 5;                // row group: 4 rows at py*4
    const int zd_s = t >> 4, zn2 = (t & 15) << 1;   // Z staging coords
    const int ek = t >> 1, ed8 = (t & 1) << 3;      // E staging coords

    float Ar[4];
    #pragma unroll
    for (int r = 0; r < 4; ++r) Ar[r] = A[n0 + (py << 2) + r];
    ull bestk[4] = {~0ull, ~0ull, ~0ull, ~0ull};

    const int kTiles = segLen / BN;
    const int nP = D >> 5;                 // 32-d periods
    for (int kt = 0; kt < kTiles; ++kt) {
        const int k0 = seg * segLen + kt * BN;
        const float* zp = zbase + (size_t)zd_s * HW + zn2;
        const float* ep = cb + (size_t)(k0 + ek) * D + ed8;
        float2 zr0 = *(const float2*)zp;           // preload period 0 (rows zd_s, zd_s+16)
        float2 zr1 = *(const float2*)(zp + (size_t)16 * HW);
        float4 e0 = *(const float4*)ep;            // E rows ed8+0..7
        float4 e1 = *(const float4*)(ep + 4);
        float4 e2 = *(const float4*)(ep + 16);     // E rows 16+ed8+0..7
        float4 e3 = *(const float4*)(ep + 20);

        float2 acc[4][8];                  // [row][col-pair], ONE sse-lane partial each
        #pragma unroll
        for (int r = 0; r < 4; ++r)
            #pragma unroll
            for (int p = 0; p < 8; ++p) acc[r][p] = make_float2(0.f, 0.f);

        // prologue: stage period 0 into buf 0, preload period 1
        *(float2*)&Zs[0][zd_s * ZP + zn2] = zr0;
        *(float2*)&Zs[0][(zd_s + 16) * ZP + zn2] = zr1;
        Es[0][(ed8 + 0) * EP + ek] = e0.x;
        Es[0][(ed8 + 1) * EP + ek] = e0.y;
        Es[0][(ed8 + 2) * EP + ek] = e0.z;
        Es[0][(ed8 + 3) * EP + ek] = e0.w;
        Es[0][(ed8 + 4) * EP + ek] = e1.x;
        Es[0][(ed8 + 5) * EP + ek] = e1.y;
        Es[0][(ed8 + 6) * EP + ek] = e1.z;
        Es[0][(ed8 + 7) * EP + ek] = e1.w;
        Es[0][(16 + ed8 + 0) * EP + ek] = e2.x;
        Es[0][(16 + ed8 + 1) * EP + ek] = e2.y;
        Es[0][(16 + ed8 + 2) * EP + ek] = e2.z;
        Es[0][(16 + ed8 + 3) * EP + ek] = e2.w;
        Es[0][(16 + ed8 + 4) * EP + ek] = e3.x;
        Es[0][(16 + ed8 + 5) * EP + ek] = e3.y;
        Es[0][(16 + ed8 + 6) * EP + ek] = e3.z;
        Es[0][(16 + ed8 + 7) * EP + ek] = e3.w;
        if (nP > 1) {
            zp += (size_t)32 * HW; ep += 32;
            zr0 = *(const float2*)zp;
            zr1 = *(const float2*)(zp + (size_t)16 * HW);
            e0 = *(const float4*)ep;
            e1 = *(const float4*)(ep + 4);
            e2 = *(const float4*)(ep + 16);
            e3 = *(const float4*)(ep + 20);
        }
        barrier_lds();                     // buf0 visible; preloads stay in flight

        for (int c = 0; c < nP; ++c) {
            const int cur = c & 1;
            #pragma unroll
            for (int u = 0; u < 8; ++u) {
                const int dl = sse + (u << 2);     // this lane's d in 0..31, ascending
                const float* zrow = &Zs[cur][dl * ZP + (py << 2)];
                float2 a01 = *(const float2*)(zrow);
                float2 a23 = *(const float2*)(zrow + 2);
                const float* er = &Es[cur][dl * EP + (px << 4)];
                float2 b0 = *(const float2*)(er + 0);
                float2 b1 = *(const float2*)(er + 2);
                float2 b2 = *(const float2*)(er + 4);
                float2 b3 = *(const float2*)(er + 6);
                pk_acc(acc[0][0], pk_mul_lo(a01, b0));
                pk_acc(acc[1][0], pk_mul_hi(a01, b0));
                pk_acc(acc[2][0], pk_mul_lo(a23, b0));
                pk_acc(acc[3][0], pk_mul_hi(a23, b0));
                pk_acc(acc[0][1], pk_mul_lo(a01, b1));
                pk_acc(acc[1][1], pk_mul_hi(a01, b1));
                pk_acc(acc[2][1], pk_mul_lo(a23, b1));
                pk_acc(acc[3][1], pk_mul_hi(a23, b1));
                pk_acc(acc[0][2], pk_mul_lo(a01, b2));
                pk_acc(acc[1][2], pk_mul_hi(a01, b2));
                pk_acc(acc[2][2], pk_mul_lo(a23, b2));
                pk_acc(acc[3][2], pk_mul_hi(a23, b2));
                pk_acc(acc[0][3], pk_mul_lo(a01, b3));
                pk_acc(acc[1][3], pk_mul_hi(a01, b3));
                pk_acc(acc[2][3], pk_mul_lo(a23, b3));
                pk_acc(acc[3][3], pk_mul_hi(a23, b3));
                float2 b4 = *(const float2*)(er + 8);
                float2 b5 = *(const float2*)(er + 10);
                float2 b6 = *(const float2*)(er + 12);
                float2 b7 = *(const float2*)(er + 14);
                pk_acc(acc[0][4], pk_mul_lo(a01, b4));
                pk_acc(acc[1][4], pk_mul_hi(a01, b4));
                pk_acc(acc[2][4], pk_mul_lo(a23, b4));
                pk_acc(acc[3][4], pk_mul_hi(a23, b4));
                pk_acc(acc[0][5], pk_mul_lo(a01, b5));
                pk_acc(acc[1][5], pk_mul_hi(a01, b5));
                pk_acc(acc[2][5], pk_mul_lo(a23, b5));
                pk_acc(acc[3][5], pk_mul_hi(a23, b5));
                pk_acc(acc[0][6], pk_mul_lo(a01, b6));
                pk_acc(acc[1][6], pk_mul_hi(a01, b6));
                pk_acc(acc[2][6], pk_mul_lo(a23, b6));
                pk_acc(acc[3][6], pk_mul_hi(a23, b6));
                pk_acc(acc[0][7], pk_mul_lo(a01, b7));
                pk_acc(acc[1][7], pk_mul_hi(a01, b7));
                pk_acc(acc[2][7], pk_mul_lo(a23, b7));
                pk_acc(acc[3][7], pk_mul_hi(a23, b7));
            }
            if (c + 1 < nP) {
                const int nxt = cur ^ 1;
                // write period c+1 (preloaded regs) while other waves MAC buf[cur]
                *(float2*)&Zs[nxt][zd_s * ZP + zn2] = zr0;
                *(float2*)&Zs[nxt][(zd_s + 16) * ZP + zn2] = zr1;
                Es[nxt][(ed8 + 0) * EP + ek] = e0.x;
                Es[nxt][(ed8 + 1) * EP + ek] = e0.y;
                Es[nxt][(ed8 + 2) * EP + ek] = e0.z;
                Es[nxt][(ed8 + 3) * EP + ek] = e0.w;
                Es[nxt][(ed8 + 4) * EP + ek] = e1.x;
                Es[nxt][(ed8 + 5) * EP + ek] = e1.y;
                Es[nxt][(ed8 + 6) * EP + ek] = e1.z;
                Es[nxt][(ed8 + 7) * EP + ek] = e1.w;
                Es[nxt][(16 + ed8 + 0) * EP + ek] = e2.x;
                Es[nxt][(16 + ed8 + 1) * EP + ek] = e2.y;
                Es[nxt][(16 + ed8 + 2) * EP + ek] = e2.z;
                Es[nxt][(16 + ed8 + 3) * EP + ek] = e2.w;
                Es[nxt][(16 + ed8 + 4) * EP + ek] = e3.x;
                Es[nxt][(16 + ed8 + 5) * EP + ek] = e3.y;
                Es[nxt][(16 + ed8 + 6) * EP + ek] = e3.z;
                Es[nxt][(16 + ed8 + 7) * EP + ek] = e3.w;
                if (c + 2 < nP) {         // in-flight across barrier + next MAC period
                    zp += (size_t)32 * HW; ep += 32;
                    zr0 = *(const float2*)zp;
                    zr1 = *(const float2*)(zp + (size_t)16 * HW);
                    e0 = *(const float4*)ep;
                    e1 = *(const float4*)(ep + 4);
                    e2 = *(const float4*)(ep + 16);
                    e3 = *(const float4*)(ep + 20);
                }
                barrier_lds();            // period c+1 visible; globals stay in flight
            }
        }
        if (nP & 1) __syncthreads();      // parity guard for odd nP (no-op at D=256)

        // epilogue: quad butterfly = exact hadd tree ((l0+l1)+(l2+l3)), then keys
        #pragma unroll
        for (int r = 0; r < 4; ++r) {
            #pragma unroll
            for (int p = 0; p < 8; ++p) {
                float2 v = acc[r][p];
                v.x = v.x + __shfl_xor(v.x, 1);
                v.y = v.y + __shfl_xor(v.y, 1);
                v.x = v.x + __shfl_xor(v.x, 2);
                v.y = v.y + __shfl_xor(v.y, 2);
                int col = k0 + (px << 4) + (p << 1);
                float dd0 = fmaf(-2.f, v.x, Ar[r]);   // fl(A - 2C), single rounding
                float dd1 = fmaf(-2.f, v.y, Ar[r]);
                ull kA = ((ull)__float_as_uint(dd0) << 32) | (unsigned)col;
                ull kB = ((ull)__float_as_uint(dd1) << 32) | (unsigned)(col + 1);
                if (kA < bestk[r]) bestk[r] = kA;
                if (kB < bestk[r]) bestk[r] = kB;
            }
        }
    }
    // merge across px groups (offsets 4,8,16 stay within the 32-lane py half-wave)
    #pragma unroll
    for (int r = 0; r < 4; ++r) {
        ull bk = bestk[r];
        #pragma unroll
        for (int off = 4; off <= 16; off <<= 1) {
            ull o = __shfl_xor(bk, off);
            if (o < bk) bk = o;
        }
        if ((t & 31) == 0)
            segkeys[(size_t)seg * N + n0 + (py << 2) + r] = bk;
    }
}

// ---------------- kernel 3: segment-min, gather z_q, STE, idx, loss partials ----------------
__global__ void out_kernel(const float* __restrict__ z, const float* __restrict__ cb,
                           const ull* __restrict__ segkeys,
                           float* __restrict__ out, float* __restrict__ parts,
                           int D, int HW, int K, int N, int nSeg) {
    #pragma clang fp contract(off)
    int n = blockIdx.x * 256 + threadIdx.x;
    int b = n / HW, hw = n % HW;
    ull bk = segkeys[n];
    for (int s = 1; s < nSeg; ++s) {
        ull o = segkeys[(size_t)s * N + n];
        if (o < bk) bk = o;
    }
    size_t zqE = (size_t)N * D;
    int raw = (int)(unsigned int)(bk & 0xffffffffULL);
    int idx = (raw >= 0 && raw < K) ? raw : 0;
    out[zqE + 1 + (size_t)n] = (float)idx;
    const float* zp = z + (size_t)b * D * HW + hw;
    const float* cp = cb + (size_t)idx * D;
    float* op = out + (size_t)b * D * HW + hw;
    float sq = 0.f;
    for (int c4 = 0; c4 < D; c4 += 4) {
        float4 q = *(const float4*)(cp + c4);
        float qv[4] = {q.x, q.y, q.z, q.w};
        #pragma unroll
        for (int i = 0; i < 4; ++i) {
            int c = c4 + i;
            float zv = zp[(size_t)c * HW];
            float diff = qv[i] - zv;
            sq = fmaf(diff, diff, sq);
            op[(size_t)c * HW] = zv + diff;
        }
    }
    #pragma unroll
    for (int off = 32; off; off >>= 1) sq += __shfl_down(sq, off, 64);
    __shared__ float red[4];
    int lane = threadIdx.x & 63, wv = threadIdx.x >> 6;
    if (lane == 0) red[wv] = sq;
    __syncthreads();
    if (threadIdx.x == 0) parts[blockIdx.x] = red[0] + red[1] + red[2] + red[3];
}

// ---------------- kernel 4: loss = mean + 0.25*mean ----------------
__global__ void loss_kernel(const float* __restrict__ parts, float* __restrict__ out,
                            int P, float inv_count, size_t zqE) {
    float v = 0.f;
    for (int i = threadIdx.x; i < P; i += 64) v += parts[i];
    #pragma unroll
    for (int off = 32; off; off >>= 1) v += __shfl_down(v, off, 64);
    if (threadIdx.x == 0) {
        float m = v * inv_count;
        out[zqE] = m + 0.25f * m;
    }
}

extern "C" void kernel_launch(void* const* d_in, const int* in_sizes, int n_in,
                              void* d_out, int out_size, void* d_ws, size_t ws_size,
                              hipStream_t stream) {
    long zE = in_sizes[0], cE = in_sizes[1];
    const float* z  = (const float*)d_in[0];
    const float* cb = (const float*)d_in[1];
    long N = (long)out_size - 1 - zE;
    long D = (N > 0 && zE % N == 0) ? zE / N : 0;
    bool okA = (N > 0) && D >= 32 && (D % 32 == 0) && (cE % D == 0) && (cE / D >= 128);
    if (!okA) {
        long tmp = zE; zE = cE; cE = tmp;
        const float* tp = z; z = cb; cb = tp;
        N = (long)out_size - 1 - zE;
        D = (N > 0 && zE % N == 0) ? zE / N : 1;
    }
    long K = cE / D;
    int HW = (N % 1024 == 0) ? 1024 : (N % 256 == 0 ? 256 : 64);
    float* out = (float*)d_out;

    int nSeg = 8;
    while (nSeg > 1 &&
           ((size_t)nSeg * N * 8 + (size_t)N * 4 + (size_t)(N / 256) * 4 > ws_size ||
            K % ((long)nSeg * BN) != 0))
        nSeg >>= 1;
    int segLen = (int)(K / nSeg);
    ull* segkeys = (ull*)d_ws;
    float* A     = (float*)((char*)d_ws + (size_t)nSeg * N * 8);
    float* parts = (float*)((char*)A + (size_t)N * 4);

    rowsumsq_kernel<<<dim3((int)(N / 256)), 256, 0, stream>>>(z, A, (int)D, HW);
    dist_kernel<<<dim3(nSeg, (int)(N / BM)), 256, 0, stream>>>(z, cb, A, segkeys,
                                                               (int)D, HW, segLen, (int)N);
    out_kernel<<<dim3((int)(N / 256)), 256, 0, stream>>>(z, cb, segkeys, out, parts,
                                                         (int)D, HW, (int)K, (int)N, nSeg);
    double cnt = (double)N * (double)D;
    loss_kernel<<<1, 64, 0, stream>>>(parts, out, (int)(N / 256),
                                      (float)(1.0 / cnt), (size_t)N * (size_t)D);
}